// Round 10
// baseline (2029.386 us; speedup 1.0000x reference)
//
#include <hip/hip_runtime.h>
#include <stdint.h>

typedef _Float16 f16;
typedef f16 v8h __attribute__((ext_vector_type(8)));
typedef f16 v4h __attribute__((ext_vector_type(4)));
typedef f16 v2h __attribute__((ext_vector_type(2)));
typedef float v4f __attribute__((ext_vector_type(4)));

#define B_   64
#define L_   49
#define ENC_ 2048
#define D_   512
#define V_   10000
#define VP_  10048
#define T_   60
#define TM_  59
#define KS_  8   // split-K for LSTM gates GEMM

__device__ __forceinline__ float sigmoidf_(float x) { return 1.f / (1.f + __expf(-x)); }
__device__ __forceinline__ float tanhf_(float x) {
  float e2 = __expf(2.f * x);
  return 1.f - 2.f / (e2 + 1.f);
}

// ---------------- one-shot f32 -> f16 casts (8 arrays) ----------------
struct CastJobs { const float* s[8]; f16* d[8]; int n4[8]; };
__global__ __launch_bounds__(256) void k_cast(CastJobs J) {
  int a = blockIdx.y;
  int i = blockIdx.x * 256 + threadIdx.x;
  if (i >= J.n4[a]) return;
  float4 v = ((const float4*)J.s[a])[i];
  v4h o; o[0] = (f16)v.x; o[1] = (f16)v.y; o[2] = (f16)v.z; o[3] = (f16)v.w;
  ((v4h*)J.d[a])[i] = o;
}

// fc_w cast with pad to 10048 columns (zero fill)
__global__ __launch_bounds__(256) void k_castpad(const float* __restrict__ s,
                                                 f16* __restrict__ d) {
  int r = blockIdx.y;
  int c4 = blockIdx.x * 256 + threadIdx.x;
  if (c4 >= VP_ / 4) return;
  int c = c4 * 4;
  v4h o;
  if (c + 3 < V_) {
    float4 v = *(const float4*)(s + (size_t)r * V_ + c);
    o[0] = (f16)v.x; o[1] = (f16)v.y; o[2] = (f16)v.z; o[3] = (f16)v.w;
  } else {
    #pragma unroll
    for (int j = 0; j < 4; j++)
      o[j] = (c + j < V_) ? (f16)s[(size_t)r * V_ + c + j] : (f16)0.f;
  }
  *(v4h*)(d + (size_t)r * VP_ + c) = o;
}

// ---------------- mean over L ----------------
__global__ __launch_bounds__(256) void k_mean(const f16* __restrict__ inh,
                                              f16* __restrict__ meanh) {
  int b = blockIdx.x, tid = threadIdx.x;
  for (int e = tid; e < ENC_; e += 256) {
    float s = 0.f;
    for (int l = 0; l < L_; l++) s += (float)inh[((size_t)(b * L_ + l)) * ENC_ + e];
    meanh[b * ENC_ + e] = (f16)(s * (1.f / 49.f));
  }
}

// ---------------- emb gather (all steps) ----------------
__global__ __launch_bounds__(128) void k_embgather(const int* __restrict__ captions,
    const float* __restrict__ embw, f16* __restrict__ emball) {
  int row = blockIdx.x;           // t*64 + b
  int t = row >> 6, b = row & 63;
  int cap = captions[b * T_ + t];
  int k = threadIdx.x * 4;
  float4 v = *(const float4*)(embw + (size_t)cap * 512 + k);
  v4h o; o[0] = (f16)v.x; o[1] = (f16)v.y; o[2] = (f16)v.z; o[3] = (f16)v.w;
  *(v4h*)(emball + (size_t)row * 512 + k) = o;
}

// ---------------- shared 64x64 f16 MFMA tile helpers ----------------
struct AR { uint4 x, y; };
struct BR { v4h b[4]; };

__device__ __forceinline__ AR load_a64(const f16* src, int lda, int tid) {
  int r = tid >> 2, k = (tid & 3) << 4;
  const f16* p = src + (size_t)r * lda + k;
  AR a; a.x = *(const uint4*)p; a.y = *(const uint4*)(p + 8); return a;
}
__device__ __forceinline__ void write_a64(const AR& a, f16 (*sA)[72], int tid) {
  int r = tid >> 2, k = (tid & 3) << 4;
  *(uint4*)&sA[r][k] = a.x; *(uint4*)&sA[r][k + 8] = a.y;
}
__device__ __forceinline__ BR load_b64(const f16* src, int ldb, int tid) {
  BR b;
  #pragma unroll
  for (int s = 0; s < 4; s++) {
    int slot = tid + s * 256;
    int kr = slot >> 4, nc = (slot & 15) << 2;
    b.b[s] = *(const v4h*)(src + (size_t)kr * ldb + nc);
  }
  return b;
}
__device__ __forceinline__ void write_b64(const BR& b, f16 (*sB)[72], int tid) {
  #pragma unroll
  for (int s = 0; s < 4; s++) {
    int slot = tid + s * 256;
    int kr = slot >> 4, nc = (slot & 15) << 2;
    sB[nc + 0][kr] = b.b[s][0]; sB[nc + 1][kr] = b.b[s][1];
    sB[nc + 2][kr] = b.b[s][2]; sB[nc + 3][kr] = b.b[s][3];
  }
}
__device__ __forceinline__ void mfma_tile(const f16 (*sA)[72], const f16 (*sB)[72],
                                          int fr, int fq, int wv, v4f* acc) {
  #pragma unroll
  for (int kk = 0; kk < 64; kk += 32) {
    v8h bfr = *(const v8h*)&sB[wv * 16 + fr][kk + fq * 8];
    #pragma unroll
    for (int mt = 0; mt < 4; mt++) {
      v8h afr = *(const v8h*)&sA[mt * 16 + fr][kk + fq * 8];
      acc[mt] = __builtin_amdgcn_mfma_f32_16x16x32_f16(afr, bfr, acc[mt], 0, 0, 0);
    }
  }
}

// rolling double-buffered K loop (depth-1 prefetch) — used by long-K one-time GEMMs
template <typename F>
__device__ __forceinline__ void gemm_db(int nch, F srcf,
    f16 (*sA)[64][72], f16 (*sB)[64][72],
    int tid, int fr, int fq, int wv, v4f* acc) {
  const f16 *ap, *bp; int la, lb;
  srcf(0, ap, la, bp, lb);
  AR ar = load_a64(ap, la, tid);
  BR br = load_b64(bp, lb, tid);
  int cur = 0;
  for (int ch = 0; ch < nch; ch++) {
    AR an = ar; BR bn = br;
    if (ch + 1 < nch) {
      srcf(ch + 1, ap, la, bp, lb);
      an = load_a64(ap, la, tid);
      bn = load_b64(bp, lb, tid);
    }
    write_a64(ar, sA[cur], tid);
    write_b64(br, sB[cur], tid);
    __syncthreads();
    mfma_tile(sA[cur], sB[cur], fr, fq, wv, acc);
    ar = an; br = bn; cur ^= 1;
  }
}

// deep-prefetch 4-chunk GEMM: ALL chunk loads issued upfront (latency paid once),
// then 4x (LDS write -> sync -> MFMA). Buffer alternation preserves the same
// write-after-read invariant as the rolling version (sync k retires reads of buf[k&1]).
template <typename F>
__device__ __forceinline__ void gemm_deep4(F srcf,
    f16 (*sA)[64][72], f16 (*sB)[64][72],
    int tid, int fr, int fq, int wv, v4f* acc) {
  const f16 *ap, *bp; int la, lb;
  srcf(0, ap, la, bp, lb); AR ar0 = load_a64(ap, la, tid); BR br0 = load_b64(bp, lb, tid);
  srcf(1, ap, la, bp, lb); AR ar1 = load_a64(ap, la, tid); BR br1 = load_b64(bp, lb, tid);
  srcf(2, ap, la, bp, lb); AR ar2 = load_a64(ap, la, tid); BR br2 = load_b64(bp, lb, tid);
  srcf(3, ap, la, bp, lb); AR ar3 = load_a64(ap, la, tid); BR br3 = load_b64(bp, lb, tid);
  write_a64(ar0, sA[0], tid); write_b64(br0, sB[0], tid);
  __syncthreads();
  mfma_tile(sA[0], sB[0], fr, fq, wv, acc);
  write_a64(ar1, sA[1], tid); write_b64(br1, sB[1], tid);
  __syncthreads();
  mfma_tile(sA[1], sB[1], fr, fq, wv, acc);
  write_a64(ar2, sA[0], tid); write_b64(br2, sB[0], tid);
  __syncthreads();
  mfma_tile(sA[0], sB[0], fr, fq, wv, acc);
  write_a64(ar3, sA[1], tid); write_b64(br3, sB[1], tid);
  __syncthreads();
  mfma_tile(sA[1], sB[1], fr, fq, wv, acc);
}

// ---------------- h0/c0 = mean @ [h_w | c_w] + bias ----------------
__global__ __launch_bounds__(256) void k_h0c0(const f16* __restrict__ meanh,
    const f16* __restrict__ hw, const float* __restrict__ hb,
    const f16* __restrict__ cw, const float* __restrict__ cb,
    float* __restrict__ h, float* __restrict__ c, f16* __restrict__ hh) {
  __shared__ __align__(16) f16 sA[2][64][72], sB[2][64][72];
  int tid = threadIdx.x, lane = tid & 63, wv = tid >> 6, fr = lane & 15, fq = lane >> 4;
  int n0 = blockIdx.x * 64;
  bool ish = n0 < 512;
  const f16* W = ish ? hw : cw;
  const float* bb = ish ? hb : cb;
  int nb = ish ? n0 : (n0 - 512);
  v4f acc[4] = {};
  auto src = [&](int ch, const f16*& ap, int& la, const f16*& bp, int& lb) {
    ap = meanh + ch * 64; la = ENC_;
    bp = W + (size_t)(ch * 64) * 512 + nb; lb = 512;
  };
  gemm_db(32, src, sA, sB, tid, fr, fq, wv, acc);
  int col = nb + wv * 16 + fr;
  float bv = bb[col];
  #pragma unroll
  for (int mt = 0; mt < 4; mt++)
    #pragma unroll
    for (int r = 0; r < 4; r++) {
      int b = mt * 16 + fq * 4 + r;
      float v = acc[mt][r] + bv;
      if (ish) { h[b * 512 + col] = v; hh[b * 512 + col] = (f16)v; }
      else       c[b * 512 + col] = v;
    }
}

// ---------------- enc_proj = input @ enc_att_w + b (f16 out) ----------------
__global__ __launch_bounds__(256) void k_ep(const f16* __restrict__ inh,
    const f16* __restrict__ Wh, const float* __restrict__ bias,
    f16* __restrict__ out) {
  __shared__ __align__(16) f16 sA[2][64][72], sB[2][64][72];
  int tid = threadIdx.x, lane = tid & 63, wv = tid >> 6, fr = lane & 15, fq = lane >> 4;
  int m0 = blockIdx.x * 64, n0 = blockIdx.y * 64;
  v4f acc[4] = {};
  auto src = [&](int ch, const f16*& ap, int& la, const f16*& bp, int& lb) {
    ap = inh + (size_t)m0 * ENC_ + ch * 64; la = ENC_;
    bp = Wh + (size_t)(ch * 64) * 512 + n0; lb = 512;
  };
  gemm_db(32, src, sA, sB, tid, fr, fq, wv, acc);
  int col = n0 + wv * 16 + fr;
  float bv = bias[col];
  #pragma unroll
  for (int mt = 0; mt < 4; mt++)
    #pragma unroll
    for (int r = 0; r < 4; r++)
      out[(size_t)(m0 + mt * 16 + fq * 4 + r) * 512 + col] = (f16)(acc[mt][r] + bv);
}

// ---------------- embproj = emball @ wih[0:512] + bih + bhh ----------------
__global__ __launch_bounds__(256) void k_embproj(const f16* __restrict__ emball,
    const f16* __restrict__ wih, const float* __restrict__ bih,
    const float* __restrict__ bhh, float* __restrict__ out) {
  __shared__ __align__(16) f16 sA[2][64][72], sB[2][64][72];
  int tid = threadIdx.x, lane = tid & 63, wv = tid >> 6, fr = lane & 15, fq = lane >> 4;
  int m0 = blockIdx.x * 64, n0 = blockIdx.y * 64;
  v4f acc[4] = {};
  auto src = [&](int ch, const f16*& ap, int& la, const f16*& bp, int& lb) {
    ap = emball + (size_t)m0 * 512 + ch * 64; la = 512;
    bp = wih + (size_t)(ch * 64) * 2048 + n0; lb = 2048;
  };
  gemm_db(8, src, sA, sB, tid, fr, fq, wv, acc);
  int col = n0 + wv * 16 + fr;
  float bv = bih[col] + bhh[col];
  #pragma unroll
  for (int mt = 0; mt < 4; mt++)
    #pragma unroll
    for (int r = 0; r < 4; r++)
      out[(size_t)(m0 + mt * 16 + fq * 4 + r) * 2048 + col] = acc[mt][r] + bv;
}

// ---------------- per-step: h @ [Wd | Wa | whh], split-K=2, raw partials ----------------
__global__ __launch_bounds__(256) void kA(const f16* __restrict__ hh,
    const f16* __restrict__ Wd, const f16* __restrict__ Wa,
    const f16* __restrict__ Ww, float* __restrict__ aout) {
  __shared__ __align__(16) f16 sA[2][64][72], sB[2][64][72];
  int tid = threadIdx.x, lane = tid & 63, wv = tid >> 6, fr = lane & 15, fq = lane >> 4;
  int n0 = blockIdx.x * 64;
  int z = blockIdx.y;
  const f16* W; int ldb, bo;
  if (n0 < 512)       { W = Wd; ldb = 512;  bo = n0; }
  else if (n0 < 2560) { W = Wa; ldb = 2048; bo = n0 - 512; }
  else                { W = Ww; ldb = 2048; bo = n0 - 2560; }
  v4f acc[4] = {};
  auto src = [&](int ch, const f16*& ap, int& la, const f16*& bp, int& lb) {
    int kl = z * 256 + ch * 64;
    ap = hh + kl; la = 512;
    bp = W + (size_t)kl * ldb + bo; lb = ldb;
  };
  gemm_deep4(src, sA, sB, tid, fr, fq, wv, acc);
  float* ao = aout + (size_t)z * 64 * 4608;
  int col = n0 + wv * 16 + fr;
  #pragma unroll
  for (int mt = 0; mt < 4; mt++)
    #pragma unroll
    for (int r = 0; r < 4; r++) {
      int b = mt * 16 + fq * 4 + r;
      ao[(size_t)b * 4608 + col] = acc[mt][r];
    }
}

// ---------------- per-step: attention + xg staging (512 threads) ----------------
__global__ __launch_bounds__(512) void kB(const f16* __restrict__ inh,
    const f16* __restrict__ encproj, const float* __restrict__ att_w,
    const float* __restrict__ att_b, const float* __restrict__ aout,
    const float* __restrict__ bd, const float* __restrict__ ba,
    const int* __restrict__ lens,
    f16* __restrict__ xg, float* __restrict__ probs, int t) {
  __shared__ float sd[512], sw[512], ss[64], sp[64];
  int b = blockIdx.x, tid = threadIdx.x;
  int lane = tid & 63, wv = tid >> 6;
  const float* a0 = aout + (size_t)b * 4608;
  const float* a1 = a0 + (size_t)64 * 4608;
  sd[tid] = a0[tid] + a1[tid] + bd[tid];
  sw[tid] = att_w[tid];
  __syncthreads();
  for (int l = wv; l < L_; l += 8) {
    const f16* ep = encproj + ((size_t)(b * L_ + l)) * 512;
    float p = 0.f;
    #pragma unroll
    for (int j = 0; j < 8; j++) {
      int a = lane + j * 64;
      float v = (float)ep[a] + sd[a];
      p = fmaf(fmaxf(v, 0.f), sw[a], p);
    }
    #pragma unroll
    for (int off = 32; off > 0; off >>= 1) p += __shfl_xor(p, off);
    if (lane == 0) ss[l] = p;
  }
  __syncthreads();
  if (wv == 0) {
    float v = (lane < L_) ? (ss[lane] + att_b[0]) : -3.0e38f;
    float m = v;
    #pragma unroll
    for (int off = 32; off > 0; off >>= 1) m = fmaxf(m, __shfl_xor(m, off));
    float e = (lane < L_) ? __expf(v - m) : 0.f;
    float s = e;
    #pragma unroll
    for (int off = 32; off > 0; off >>= 1) s += __shfl_xor(s, off);
    float pr = e / s;
    if (lane < L_) {
      sp[lane] = pr;
      bool act = t < (lens[b] - 1);
      probs[((size_t)b * TM_ + t) * L_ + lane] = act ? pr : 0.f;
    }
  }
  __syncthreads();
  int e = tid * 4;
  float av0 = 0, av1 = 0, av2 = 0, av3 = 0;
  const f16* ip = inh + (size_t)b * L_ * ENC_ + e;
  for (int l = 0; l < L_; l++) {
    v4h x = *(const v4h*)(ip + (size_t)l * ENC_);
    float pl = sp[l];
    av0 = fmaf(pl, (float)x[0], av0); av1 = fmaf(pl, (float)x[1], av1);
    av2 = fmaf(pl, (float)x[2], av2); av3 = fmaf(pl, (float)x[3], av3);
  }
  float g0 = sigmoidf_(a0[512 + e]     + a1[512 + e]     + ba[e]);
  float g1 = sigmoidf_(a0[512 + e + 1] + a1[512 + e + 1] + ba[e + 1]);
  float g2 = sigmoidf_(a0[512 + e + 2] + a1[512 + e + 2] + ba[e + 2]);
  float g3 = sigmoidf_(a0[512 + e + 3] + a1[512 + e + 3] + ba[e + 3]);
  v4h o;
  o[0] = (f16)(av0 * g0); o[1] = (f16)(av1 * g1);
  o[2] = (f16)(av2 * g2); o[3] = (f16)(av3 * g3);
  *(v4h*)(xg + (size_t)b * 2048 + e) = o;
}

// ---------------- per-step: xg @ wih[512:2560]  (split-K = 8) ----------------
__global__ __launch_bounds__(256) void kC(const f16* __restrict__ xg,
    const f16* __restrict__ wih, float* __restrict__ part) {
  __shared__ __align__(16) f16 sA[2][64][72], sB[2][64][72];
  int tid = threadIdx.x, lane = tid & 63, wv = tid >> 6, fr = lane & 15, fq = lane >> 4;
  int n0 = blockIdx.x * 64;
  int z = blockIdx.y;
  v4f acc[4] = {};
  auto src = [&](int ch, const f16*& ap, int& la, const f16*& bp, int& lb) {
    int kl = z * 256 + ch * 64;
    ap = xg + kl; la = 2048;
    bp = wih + (size_t)(512 + kl) * 2048 + n0; lb = 2048;
  };
  gemm_deep4(src, sA, sB, tid, fr, fq, wv, acc);
  int col = n0 + wv * 16 + fr;
  float* pp = part + ((size_t)z * 64) * 2048;
  #pragma unroll
  for (int mt = 0; mt < 4; mt++)
    #pragma unroll
    for (int r = 0; r < 4; r++) {
      int b = mt * 16 + fq * 4 + r;
      pp[(size_t)b * 2048 + col] = acc[mt][r];
    }
}

// ---------------- per-step: reduce partials + LSTM cell + state ----------------
__global__ __launch_bounds__(256) void kD(const float* __restrict__ part,
    const float* __restrict__ embproj, const float* __restrict__ aout,
    const int* __restrict__ lens, float* __restrict__ h, float* __restrict__ c,
    f16* __restrict__ hh, f16* __restrict__ hseq, int t) {
  int b = blockIdx.x;
  int d = blockIdx.y * 256 + threadIdx.x;
  const float* a0 = aout + (size_t)b * 4608 + 2560;
  const float* a1 = a0 + (size_t)64 * 4608;
  float g[4];
  #pragma unroll
  for (int q = 0; q < 4; q++) {
    int n = q * 512 + d;
    float s = embproj[((size_t)(t * 64 + b)) * 2048 + n] + a0[n] + a1[n];
    #pragma unroll
    for (int z = 0; z < KS_; z++) s += part[((size_t)(z * 64 + b)) * 2048 + n];
    g[q] = s;
  }
  float i_ = sigmoidf_(g[0]);
  float f_ = sigmoidf_(g[1]);
  float gg = tanhf_(g[2]);
  float o_ = sigmoidf_(g[3]);
  float cold = c[b * 512 + d], hold = h[b * 512 + d];
  float cn = f_ * cold + i_ * gg;
  float hn = o_ * tanhf_(cn);
  bool act = t < (lens[b] - 1);
  float ho = act ? hn : hold;
  float co = act ? cn : cold;
  h[b * 512 + d] = ho;
  c[b * 512 + d] = co;
  hh[b * 512 + d] = (f16)ho;
  hseq[((size_t)t * 64 + b) * 512 + d] = (f16)ho;
}

// ---------------- final: preds = hseq @ fc_w + fc_b (padded W) ----------------
__global__ __launch_bounds__(256) void k_fc(const f16* __restrict__ hseq,
    const f16* __restrict__ W, const float* __restrict__ bias,
    const int* __restrict__ lens, float* __restrict__ preds) {
  __shared__ __align__(16) f16 sA[2][64][72], sB[2][64][72];
  int tid = threadIdx.x, lane = tid & 63, wv = tid >> 6, fr = lane & 15, fq = lane >> 4;
  int t = blockIdx.x, n0 = blockIdx.y * 64;
  v4f acc[4] = {};
  auto src = [&](int ch, const f16*& ap, int& la, const f16*& bp, int& lb) {
    ap = hseq + ((size_t)t * 64) * 512 + ch * 64; la = 512;
    bp = W + (size_t)(ch * 64) * VP_ + n0; lb = VP_;
  };
  gemm_db(8, src, sA, sB, tid, fr, fq, wv, acc);
  int col = n0 + wv * 16 + fr;
  if (col < V_) {
    float bv = bias[col];
    #pragma unroll
    for (int mt = 0; mt < 4; mt++)
      #pragma unroll
      for (int r = 0; r < 4; r++) {
        int b = mt * 16 + fq * 4 + r;
        bool act = t < (lens[b] - 1);
        preds[((size_t)b * TM_ + t) * (size_t)V_ + col] = act ? (acc[mt][r] + bv) : 0.f;
      }
  }
}

extern "C" void kernel_launch(void* const* d_in, const int* in_sizes, int n_in,
                              void* d_out, int out_size, void* d_ws, size_t ws_size,
                              hipStream_t stream) {
  (void)in_sizes; (void)n_in; (void)out_size; (void)ws_size;
  const float* input     = (const float*)d_in[0];
  const int*   captions  = (const int*)d_in[1];
  const int*   lens      = (const int*)d_in[2];
  const float* embw      = (const float*)d_in[3];
  const float* enc_att_w = (const float*)d_in[4];
  const float* enc_att_b = (const float*)d_in[5];
  const float* dec_att_w = (const float*)d_in[6];
  const float* dec_att_b = (const float*)d_in[7];
  const float* att_w     = (const float*)d_in[8];
  const float* att_b     = (const float*)d_in[9];
  const float* h_w       = (const float*)d_in[10];
  const float* h_b       = (const float*)d_in[11];
  const float* c_w       = (const float*)d_in[12];
  const float* c_b       = (const float*)d_in[13];
  const float* actv_w    = (const float*)d_in[14];
  const float* actv_b    = (const float*)d_in[15];
  const float* wih       = (const float*)d_in[16];
  const float* whh       = (const float*)d_in[17];
  const float* bih       = (const float*)d_in[18];
  const float* bhh       = (const float*)d_in[19];
  const float* fc_w      = (const float*)d_in[20];
  const float* fc_b      = (const float*)d_in[21];

  float* preds = (float*)d_out;
  float* probs = preds + (size_t)B_ * TM_ * V_;

  char* w = (char*)d_ws;
  auto alloc = [&](size_t bytes) -> char* {
    char* p = w; w += (bytes + 255) & ~(size_t)255; return p;
  };
  f16* input_h = (f16*)alloc((size_t)6422528 * 2);
  f16* eaw_h   = (f16*)alloc((size_t)1048576 * 2);
  f16* daw_h   = (f16*)alloc((size_t)262144 * 2);
  f16* avw_h   = (f16*)alloc((size_t)1048576 * 2);
  f16* wih_h   = (f16*)alloc((size_t)5242880 * 2);
  f16* whh_h   = (f16*)alloc((size_t)1048576 * 2);
  f16* hw_h    = (f16*)alloc((size_t)1048576 * 2);
  f16* cw_h    = (f16*)alloc((size_t)1048576 * 2);
  f16* fcw_pad = (f16*)alloc((size_t)512 * VP_ * 2);
  f16* meanh   = (f16*)alloc((size_t)B_ * ENC_ * 2);
  f16* encproj = (f16*)alloc((size_t)3136 * 512 * 2);
  float* hbuf  = (float*)alloc((size_t)B_ * 512 * 4);
  float* cbuf  = (float*)alloc((size_t)B_ * 512 * 4);
  f16*   hh    = (f16*)alloc((size_t)B_ * 512 * 2);
  float* aout  = (float*)alloc((size_t)2 * 64 * 4608 * 4);
  f16*   xg    = (f16*)alloc((size_t)B_ * 2048 * 2);
  float* part  = (float*)alloc((size_t)KS_ * B_ * 2048 * 4);
  f16*   hseq  = (f16*)alloc((size_t)TM_ * B_ * 512 * 2);
  f16*   embal = (f16*)alloc((size_t)TM_ * B_ * 512 * 2);
  float* embpj = (float*)alloc((size_t)TM_ * B_ * 2048 * 4);

  CastJobs J;
  J.s[0] = input;     J.d[0] = input_h; J.n4[0] = 6422528 / 4;
  J.s[1] = enc_att_w; J.d[1] = eaw_h;   J.n4[1] = 1048576 / 4;
  J.s[2] = dec_att_w; J.d[2] = daw_h;   J.n4[2] = 262144 / 4;
  J.s[3] = actv_w;    J.d[3] = avw_h;   J.n4[3] = 1048576 / 4;
  J.s[4] = wih;       J.d[4] = wih_h;   J.n4[4] = 5242880 / 4;
  J.s[5] = whh;       J.d[5] = whh_h;   J.n4[5] = 1048576 / 4;
  J.s[6] = h_w;       J.d[6] = hw_h;    J.n4[6] = 1048576 / 4;
  J.s[7] = c_w;       J.d[7] = cw_h;    J.n4[7] = 1048576 / 4;
  k_cast<<<dim3((1605632 + 255) / 256, 8), 256, 0, stream>>>(J);
  k_castpad<<<dim3((VP_ / 4 + 255) / 256, 512), 256, 0, stream>>>(fc_w, fcw_pad);

  k_mean<<<64, 256, 0, stream>>>(input_h, meanh);
  k_embgather<<<TM_ * B_, 128, 0, stream>>>(captions, embw, embal);
  k_h0c0<<<16, 256, 0, stream>>>(meanh, hw_h, h_b, cw_h, c_b, hbuf, cbuf, hh);
  k_ep<<<dim3(49, 8), 256, 0, stream>>>(input_h, eaw_h, enc_att_b, encproj);
  k_embproj<<<dim3(TM_, 32), 256, 0, stream>>>(embal, wih_h, bih, bhh, embpj);

  for (int t = 0; t < TM_; t++) {
    kA<<<dim3(72, 2), 256, 0, stream>>>(hh, daw_h, avw_h, whh_h, aout);
    kB<<<64, 512, 0, stream>>>(input_h, encproj, att_w, att_b, aout,
                               dec_att_b, actv_b, lens, xg, probs, t);
    kC<<<dim3(32, KS_), 256, 0, stream>>>(xg, wih_h, part);
    kD<<<dim3(64, 2), 256, 0, stream>>>(part, embpj, aout, lens, hbuf, cbuf,
                                        hh, hseq, t);
  }
  k_fc<<<dim3(59, 157), 256, 0, stream>>>(hseq, fcw_pad, fc_b, lens, preds);
}

// Round 11
// 1801.502 us; speedup vs baseline: 1.1265x; 1.1265x over previous
//
#include <hip/hip_runtime.h>
#include <stdint.h>

typedef _Float16 f16;
typedef f16 v8h __attribute__((ext_vector_type(8)));
typedef f16 v4h __attribute__((ext_vector_type(4)));
typedef f16 v2h __attribute__((ext_vector_type(2)));
typedef float v4f __attribute__((ext_vector_type(4)));

#define B_   64
#define L_   49
#define ENC_ 2048
#define D_   512
#define V_   10000
#define VP_  10048
#define T_   60
#define TM_  59
#define KS_  8   // split-K for LSTM gates GEMM

__device__ __forceinline__ float sigmoidf_(float x) { return 1.f / (1.f + __expf(-x)); }
__device__ __forceinline__ float tanhf_(float x) {
  float e2 = __expf(2.f * x);
  return 1.f - 2.f / (e2 + 1.f);
}

// ---------------- one-shot input cast (f32 -> f16) ----------------
__global__ __launch_bounds__(256) void k_castone(const float* __restrict__ s,
                                                 f16* __restrict__ d, int n4) {
  int i = blockIdx.x * 256 + threadIdx.x;
  if (i >= n4) return;
  float4 v = ((const float4*)s)[i];
  v4h o; o[0] = (f16)v.x; o[1] = (f16)v.y; o[2] = (f16)v.z; o[3] = (f16)v.w;
  ((v4h*)d)[i] = o;
}

// ---------------- one-shot cast + transpose: f32 [K][N] -> f16 [N][K] ----------------
struct TrJobs { const float* s[8]; f16* d[8]; int K[8]; int N[8]; int tiles[8]; };
__global__ __launch_bounds__(256) void k_casttr(TrJobs J) {
  int a = blockIdx.y;
  int tile = blockIdx.x;
  if (tile >= J.tiles[a]) return;
  int K = J.K[a], N = J.N[a];
  int ntn = N >> 6;
  int k0 = (tile / ntn) * 64, n0 = (tile % ntn) * 64;
  __shared__ f16 tl[64][65];
  const float* s = J.s[a];
  f16* d = J.d[a];
  int tid = threadIdx.x;
  int cr = tid >> 6, cc = tid & 63;
  #pragma unroll
  for (int r = 0; r < 16; r++) {
    int row = r * 4 + cr;
    tl[row][cc] = (f16)s[(size_t)(k0 + row) * N + n0 + cc];
  }
  __syncthreads();
  #pragma unroll
  for (int r = 0; r < 16; r++) {
    int row = r * 4 + cr;                 // n-index within tile
    d[(size_t)(n0 + row) * K + k0 + cc] = tl[cc][row];
  }
}

// fc_w cast with pad to 10048 columns (zero fill)
__global__ __launch_bounds__(256) void k_castpad(const float* __restrict__ s,
                                                 f16* __restrict__ d) {
  int r = blockIdx.y;
  int c4 = blockIdx.x * 256 + threadIdx.x;
  if (c4 >= VP_ / 4) return;
  int c = c4 * 4;
  v4h o;
  if (c + 3 < V_) {
    float4 v = *(const float4*)(s + (size_t)r * V_ + c);
    o[0] = (f16)v.x; o[1] = (f16)v.y; o[2] = (f16)v.z; o[3] = (f16)v.w;
  } else {
    #pragma unroll
    for (int j = 0; j < 4; j++)
      o[j] = (c + j < V_) ? (f16)s[(size_t)r * V_ + c + j] : (f16)0.f;
  }
  *(v4h*)(d + (size_t)r * VP_ + c) = o;
}

// ---------------- mean over L ----------------
__global__ __launch_bounds__(256) void k_mean(const f16* __restrict__ inh,
                                              f16* __restrict__ meanh) {
  int b = blockIdx.x, tid = threadIdx.x;
  for (int e = tid; e < ENC_; e += 256) {
    float s = 0.f;
    for (int l = 0; l < L_; l++) s += (float)inh[((size_t)(b * L_ + l)) * ENC_ + e];
    meanh[b * ENC_ + e] = (f16)(s * (1.f / 49.f));
  }
}

// ---------------- emb gather (all steps) ----------------
__global__ __launch_bounds__(128) void k_embgather(const int* __restrict__ captions,
    const float* __restrict__ embw, f16* __restrict__ emball) {
  int row = blockIdx.x;           // t*64 + b
  int t = row >> 6, b = row & 63;
  int cap = captions[b * T_ + t];
  int k = threadIdx.x * 4;
  float4 v = *(const float4*)(embw + (size_t)cap * 512 + k);
  v4h o; o[0] = (f16)v.x; o[1] = (f16)v.y; o[2] = (f16)v.z; o[3] = (f16)v.w;
  *(v4h*)(emball + (size_t)row * 512 + k) = o;
}

// ---------------- shared 64x64 f16 MFMA tile helpers ----------------
struct AR { uint4 x, y; };
struct BR { v4h b[4]; };

__device__ __forceinline__ AR load_a64(const f16* src, int lda, int tid) {
  int r = tid >> 2, k = (tid & 3) << 4;
  const f16* p = src + (size_t)r * lda + k;
  AR a; a.x = *(const uint4*)p; a.y = *(const uint4*)(p + 8); return a;
}
__device__ __forceinline__ void write_a64(const AR& a, f16 (*sA)[72], int tid) {
  int r = tid >> 2, k = (tid & 3) << 4;
  *(uint4*)&sA[r][k] = a.x; *(uint4*)&sA[r][k + 8] = a.y;
}
__device__ __forceinline__ BR load_b64(const f16* src, int ldb, int tid) {
  BR b;
  #pragma unroll
  for (int s = 0; s < 4; s++) {
    int slot = tid + s * 256;
    int kr = slot >> 4, nc = (slot & 15) << 2;
    b.b[s] = *(const v4h*)(src + (size_t)kr * ldb + nc);
  }
  return b;
}
__device__ __forceinline__ void write_b64(const BR& b, f16 (*sB)[72], int tid) {
  #pragma unroll
  for (int s = 0; s < 4; s++) {
    int slot = tid + s * 256;
    int kr = slot >> 4, nc = (slot & 15) << 2;
    sB[nc + 0][kr] = b.b[s][0]; sB[nc + 1][kr] = b.b[s][1];
    sB[nc + 2][kr] = b.b[s][2]; sB[nc + 3][kr] = b.b[s][3];
  }
}
__device__ __forceinline__ void mfma_tile(const f16 (*sA)[72], const f16 (*sB)[72],
                                          int fr, int fq, int wv, v4f* acc) {
  #pragma unroll
  for (int kk = 0; kk < 64; kk += 32) {
    v8h bfr = *(const v8h*)&sB[wv * 16 + fr][kk + fq * 8];
    #pragma unroll
    for (int mt = 0; mt < 4; mt++) {
      v8h afr = *(const v8h*)&sA[mt * 16 + fr][kk + fq * 8];
      acc[mt] = __builtin_amdgcn_mfma_f32_16x16x32_f16(afr, bfr, acc[mt], 0, 0, 0);
    }
  }
}

// rolling double-buffered K loop, BOTH operands staged row-major (B pre-transposed).
// Per chunk per thread: 4x 16B global loads + 4x ds_write_b128 (no scalar scatter).
template <typename F>
__device__ __forceinline__ void gemm_dbT(int nch, F srcf,
    f16 (*sA)[64][72], f16 (*sB)[64][72],
    int tid, int fr, int fq, int wv, v4f* acc) {
  const f16 *ap, *bp; int la, lb;
  srcf(0, ap, la, bp, lb);
  AR ar = load_a64(ap, la, tid);
  AR br = load_a64(bp, lb, tid);
  int cur = 0;
  for (int ch = 0; ch < nch; ch++) {
    AR an = ar, bn = br;
    if (ch + 1 < nch) {
      srcf(ch + 1, ap, la, bp, lb);
      an = load_a64(ap, la, tid);
      bn = load_a64(bp, lb, tid);
    }
    write_a64(ar, sA[cur], tid);
    write_a64(br, sB[cur], tid);
    __syncthreads();
    mfma_tile(sA[cur], sB[cur], fr, fq, wv, acc);
    ar = an; br = bn; cur ^= 1;
  }
}

// legacy path (B scattered from row-major [k][n]) — used only by one-time k_fc
template <typename F>
__device__ __forceinline__ void gemm_db(int nch, F srcf,
    f16 (*sA)[64][72], f16 (*sB)[64][72],
    int tid, int fr, int fq, int wv, v4f* acc) {
  const f16 *ap, *bp; int la, lb;
  srcf(0, ap, la, bp, lb);
  AR ar = load_a64(ap, la, tid);
  BR br = load_b64(bp, lb, tid);
  int cur = 0;
  for (int ch = 0; ch < nch; ch++) {
    AR an = ar; BR bn = br;
    if (ch + 1 < nch) {
      srcf(ch + 1, ap, la, bp, lb);
      an = load_a64(ap, la, tid);
      bn = load_b64(bp, lb, tid);
    }
    write_a64(ar, sA[cur], tid);
    write_b64(br, sB[cur], tid);
    __syncthreads();
    mfma_tile(sA[cur], sB[cur], fr, fq, wv, acc);
    ar = an; br = bn; cur ^= 1;
  }
}

// ---------------- h0/c0 = mean @ [h_w | c_w] + bias (transposed W) ----------------
__global__ __launch_bounds__(256) void k_h0c0(const f16* __restrict__ meanh,
    const f16* __restrict__ hwT, const float* __restrict__ hb,
    const f16* __restrict__ cwT, const float* __restrict__ cb,
    float* __restrict__ h, float* __restrict__ c, f16* __restrict__ hh) {
  __shared__ __align__(16) f16 sA[2][64][72], sB[2][64][72];
  int tid = threadIdx.x, lane = tid & 63, wv = tid >> 6, fr = lane & 15, fq = lane >> 4;
  int n0 = blockIdx.x * 64;
  bool ish = n0 < 512;
  const f16* WT = ish ? hwT : cwT;
  const float* bb = ish ? hb : cb;
  int nb = ish ? n0 : (n0 - 512);
  v4f acc[4] = {};
  auto src = [&](int ch, const f16*& ap, int& la, const f16*& bp, int& lb) {
    ap = meanh + ch * 64; la = ENC_;
    bp = WT + (size_t)nb * ENC_ + ch * 64; lb = ENC_;
  };
  gemm_dbT(32, src, sA, sB, tid, fr, fq, wv, acc);
  int col = nb + wv * 16 + fr;
  float bv = bb[col];
  #pragma unroll
  for (int mt = 0; mt < 4; mt++)
    #pragma unroll
    for (int r = 0; r < 4; r++) {
      int b = mt * 16 + fq * 4 + r;
      float v = acc[mt][r] + bv;
      if (ish) { h[b * 512 + col] = v; hh[b * 512 + col] = (f16)v; }
      else       c[b * 512 + col] = v;
    }
}

// ---------------- enc_proj = input @ enc_att_w + b (f16 out, transposed W) ----------------
__global__ __launch_bounds__(256) void k_ep(const f16* __restrict__ inh,
    const f16* __restrict__ WT, const float* __restrict__ bias,
    f16* __restrict__ out) {
  __shared__ __align__(16) f16 sA[2][64][72], sB[2][64][72];
  int tid = threadIdx.x, lane = tid & 63, wv = tid >> 6, fr = lane & 15, fq = lane >> 4;
  int m0 = blockIdx.x * 64, n0 = blockIdx.y * 64;
  v4f acc[4] = {};
  auto src = [&](int ch, const f16*& ap, int& la, const f16*& bp, int& lb) {
    ap = inh + (size_t)m0 * ENC_ + ch * 64; la = ENC_;
    bp = WT + (size_t)n0 * ENC_ + ch * 64; lb = ENC_;
  };
  gemm_dbT(32, src, sA, sB, tid, fr, fq, wv, acc);
  int col = n0 + wv * 16 + fr;
  float bv = bias[col];
  #pragma unroll
  for (int mt = 0; mt < 4; mt++)
    #pragma unroll
    for (int r = 0; r < 4; r++)
      out[(size_t)(m0 + mt * 16 + fq * 4 + r) * 512 + col] = (f16)(acc[mt][r] + bv);
}

// ---------------- embproj = emball @ wih[0:512] + bih + bhh (transposed W) ----------------
__global__ __launch_bounds__(256) void k_embproj(const f16* __restrict__ emball,
    const f16* __restrict__ wih0T, const float* __restrict__ bih,
    const float* __restrict__ bhh, float* __restrict__ out) {
  __shared__ __align__(16) f16 sA[2][64][72], sB[2][64][72];
  int tid = threadIdx.x, lane = tid & 63, wv = tid >> 6, fr = lane & 15, fq = lane >> 4;
  int m0 = blockIdx.x * 64, n0 = blockIdx.y * 64;
  v4f acc[4] = {};
  auto src = [&](int ch, const f16*& ap, int& la, const f16*& bp, int& lb) {
    ap = emball + (size_t)m0 * 512 + ch * 64; la = 512;
    bp = wih0T + (size_t)n0 * 512 + ch * 64; lb = 512;
  };
  gemm_dbT(8, src, sA, sB, tid, fr, fq, wv, acc);
  int col = n0 + wv * 16 + fr;
  float bv = bih[col] + bhh[col];
  #pragma unroll
  for (int mt = 0; mt < 4; mt++)
    #pragma unroll
    for (int r = 0; r < 4; r++)
      out[(size_t)(m0 + mt * 16 + fq * 4 + r) * 2048 + col] = acc[mt][r] + bv;
}

// ---------------- per-step: h @ [Wd | Wa | whh], split-K=2, transposed W ----------------
__global__ __launch_bounds__(256) void kA(const f16* __restrict__ hh,
    const f16* __restrict__ dawT, const f16* __restrict__ avwT,
    const f16* __restrict__ whhT, float* __restrict__ aout) {
  __shared__ __align__(16) f16 sA[2][64][72], sB[2][64][72];
  int tid = threadIdx.x, lane = tid & 63, wv = tid >> 6, fr = lane & 15, fq = lane >> 4;
  int n0 = blockIdx.x * 64;
  int z = blockIdx.y;
  const f16* WT; int bo;
  if (n0 < 512)       { WT = dawT; bo = n0; }
  else if (n0 < 2560) { WT = avwT; bo = n0 - 512; }
  else                { WT = whhT; bo = n0 - 2560; }
  v4f acc[4] = {};
  auto src = [&](int ch, const f16*& ap, int& la, const f16*& bp, int& lb) {
    int kl = z * 256 + ch * 64;
    ap = hh + kl; la = 512;
    bp = WT + (size_t)bo * 512 + kl; lb = 512;
  };
  gemm_dbT(4, src, sA, sB, tid, fr, fq, wv, acc);
  float* ao = aout + (size_t)z * 64 * 4608;
  int col = n0 + wv * 16 + fr;
  #pragma unroll
  for (int mt = 0; mt < 4; mt++)
    #pragma unroll
    for (int r = 0; r < 4; r++) {
      int b = mt * 16 + fq * 4 + r;
      ao[(size_t)b * 4608 + col] = acc[mt][r];
    }
}

// ---------------- per-step: attention + xg staging (512 threads) ----------------
__global__ __launch_bounds__(512) void kB(const f16* __restrict__ inh,
    const f16* __restrict__ encproj, const float* __restrict__ att_w,
    const float* __restrict__ att_b, const float* __restrict__ aout,
    const float* __restrict__ bd, const float* __restrict__ ba,
    const int* __restrict__ lens,
    f16* __restrict__ xg, float* __restrict__ probs, int t) {
  __shared__ float sd[512], sw[512], ss[64], sp[64];
  int b = blockIdx.x, tid = threadIdx.x;
  int lane = tid & 63, wv = tid >> 6;
  const float* a0 = aout + (size_t)b * 4608;
  const float* a1 = a0 + (size_t)64 * 4608;
  sd[tid] = a0[tid] + a1[tid] + bd[tid];
  sw[tid] = att_w[tid];
  __syncthreads();
  for (int l = wv; l < L_; l += 8) {
    const f16* ep = encproj + ((size_t)(b * L_ + l)) * 512;
    float p = 0.f;
    #pragma unroll
    for (int j = 0; j < 8; j++) {
      int a = lane + j * 64;
      float v = (float)ep[a] + sd[a];
      p = fmaf(fmaxf(v, 0.f), sw[a], p);
    }
    #pragma unroll
    for (int off = 32; off > 0; off >>= 1) p += __shfl_xor(p, off);
    if (lane == 0) ss[l] = p;
  }
  __syncthreads();
  if (wv == 0) {
    float v = (lane < L_) ? (ss[lane] + att_b[0]) : -3.0e38f;
    float m = v;
    #pragma unroll
    for (int off = 32; off > 0; off >>= 1) m = fmaxf(m, __shfl_xor(m, off));
    float e = (lane < L_) ? __expf(v - m) : 0.f;
    float s = e;
    #pragma unroll
    for (int off = 32; off > 0; off >>= 1) s += __shfl_xor(s, off);
    float pr = e / s;
    if (lane < L_) {
      sp[lane] = pr;
      bool act = t < (lens[b] - 1);
      probs[((size_t)b * TM_ + t) * L_ + lane] = act ? pr : 0.f;
    }
  }
  __syncthreads();
  int e = tid * 4;
  float av0 = 0, av1 = 0, av2 = 0, av3 = 0;
  const f16* ip = inh + (size_t)b * L_ * ENC_ + e;
  for (int l = 0; l < L_; l++) {
    v4h x = *(const v4h*)(ip + (size_t)l * ENC_);
    float pl = sp[l];
    av0 = fmaf(pl, (float)x[0], av0); av1 = fmaf(pl, (float)x[1], av1);
    av2 = fmaf(pl, (float)x[2], av2); av3 = fmaf(pl, (float)x[3], av3);
  }
  float g0 = sigmoidf_(a0[512 + e]     + a1[512 + e]     + ba[e]);
  float g1 = sigmoidf_(a0[512 + e + 1] + a1[512 + e + 1] + ba[e + 1]);
  float g2 = sigmoidf_(a0[512 + e + 2] + a1[512 + e + 2] + ba[e + 2]);
  float g3 = sigmoidf_(a0[512 + e + 3] + a1[512 + e + 3] + ba[e + 3]);
  v4h o;
  o[0] = (f16)(av0 * g0); o[1] = (f16)(av1 * g1);
  o[2] = (f16)(av2 * g2); o[3] = (f16)(av3 * g3);
  *(v4h*)(xg + (size_t)b * 2048 + e) = o;
}

// ---------------- per-step: xg @ wih[512:2560]  (split-K = 8, transposed W) ----------------
__global__ __launch_bounds__(256) void kC(const f16* __restrict__ xg,
    const f16* __restrict__ wih2T, float* __restrict__ part) {
  __shared__ __align__(16) f16 sA[2][64][72], sB[2][64][72];
  int tid = threadIdx.x, lane = tid & 63, wv = tid >> 6, fr = lane & 15, fq = lane >> 4;
  int n0 = blockIdx.x * 64;
  int z = blockIdx.y;
  v4f acc[4] = {};
  auto src = [&](int ch, const f16*& ap, int& la, const f16*& bp, int& lb) {
    int kl = z * 256 + ch * 64;
    ap = xg + kl; la = 2048;
    bp = wih2T + (size_t)n0 * 2048 + kl; lb = 2048;
  };
  gemm_dbT(4, src, sA, sB, tid, fr, fq, wv, acc);
  int col = n0 + wv * 16 + fr;
  float* pp = part + ((size_t)z * 64) * 2048;
  #pragma unroll
  for (int mt = 0; mt < 4; mt++)
    #pragma unroll
    for (int r = 0; r < 4; r++) {
      int b = mt * 16 + fq * 4 + r;
      pp[(size_t)b * 2048 + col] = acc[mt][r];
    }
}

// ---------------- per-step: reduce partials + LSTM cell + state ----------------
__global__ __launch_bounds__(256) void kD(const float* __restrict__ part,
    const float* __restrict__ embproj, const float* __restrict__ aout,
    const int* __restrict__ lens, float* __restrict__ h, float* __restrict__ c,
    f16* __restrict__ hh, f16* __restrict__ hseq, int t) {
  int b = blockIdx.x;
  int d = blockIdx.y * 256 + threadIdx.x;
  const float* a0 = aout + (size_t)b * 4608 + 2560;
  const float* a1 = a0 + (size_t)64 * 4608;
  float g[4];
  #pragma unroll
  for (int q = 0; q < 4; q++) {
    int n = q * 512 + d;
    float s = embproj[((size_t)(t * 64 + b)) * 2048 + n] + a0[n] + a1[n];
    #pragma unroll
    for (int z = 0; z < KS_; z++) s += part[((size_t)(z * 64 + b)) * 2048 + n];
    g[q] = s;
  }
  float i_ = sigmoidf_(g[0]);
  float f_ = sigmoidf_(g[1]);
  float gg = tanhf_(g[2]);
  float o_ = sigmoidf_(g[3]);
  float cold = c[b * 512 + d], hold = h[b * 512 + d];
  float cn = f_ * cold + i_ * gg;
  float hn = o_ * tanhf_(cn);
  bool act = t < (lens[b] - 1);
  float ho = act ? hn : hold;
  float co = act ? cn : cold;
  h[b * 512 + d] = ho;
  c[b * 512 + d] = co;
  hh[b * 512 + d] = (f16)ho;
  hseq[((size_t)t * 64 + b) * 512 + d] = (f16)ho;
}

// ---------------- final: preds = hseq @ fc_w + fc_b (padded W, legacy staging) ----------------
__global__ __launch_bounds__(256) void k_fc(const f16* __restrict__ hseq,
    const f16* __restrict__ W, const float* __restrict__ bias,
    const int* __restrict__ lens, float* __restrict__ preds) {
  __shared__ __align__(16) f16 sA[2][64][72], sB[2][64][72];
  int tid = threadIdx.x, lane = tid & 63, wv = tid >> 6, fr = lane & 15, fq = lane >> 4;
  int t = blockIdx.x, n0 = blockIdx.y * 64;
  v4f acc[4] = {};
  auto src = [&](int ch, const f16*& ap, int& la, const f16*& bp, int& lb) {
    ap = hseq + ((size_t)t * 64) * 512 + ch * 64; la = 512;
    bp = W + (size_t)(ch * 64) * VP_ + n0; lb = VP_;
  };
  gemm_db(8, src, sA, sB, tid, fr, fq, wv, acc);
  int col = n0 + wv * 16 + fr;
  if (col < V_) {
    float bv = bias[col];
    #pragma unroll
    for (int mt = 0; mt < 4; mt++)
      #pragma unroll
      for (int r = 0; r < 4; r++) {
        int b = mt * 16 + fq * 4 + r;
        bool act = t < (lens[b] - 1);
        preds[((size_t)b * TM_ + t) * (size_t)V_ + col] = act ? (acc[mt][r] + bv) : 0.f;
      }
  }
}

extern "C" void kernel_launch(void* const* d_in, const int* in_sizes, int n_in,
                              void* d_out, int out_size, void* d_ws, size_t ws_size,
                              hipStream_t stream) {
  (void)in_sizes; (void)n_in; (void)out_size; (void)ws_size;
  const float* input     = (const float*)d_in[0];
  const int*   captions  = (const int*)d_in[1];
  const int*   lens      = (const int*)d_in[2];
  const float* embw      = (const float*)d_in[3];
  const float* enc_att_w = (const float*)d_in[4];
  const float* enc_att_b = (const float*)d_in[5];
  const float* dec_att_w = (const float*)d_in[6];
  const float* dec_att_b = (const float*)d_in[7];
  const float* att_w     = (const float*)d_in[8];
  const float* att_b     = (const float*)d_in[9];
  const float* h_w       = (const float*)d_in[10];
  const float* h_b       = (const float*)d_in[11];
  const float* c_w       = (const float*)d_in[12];
  const float* c_b       = (const float*)d_in[13];
  const float* actv_w    = (const float*)d_in[14];
  const float* actv_b    = (const float*)d_in[15];
  const float* wih       = (const float*)d_in[16];
  const float* whh       = (const float*)d_in[17];
  const float* bih       = (const float*)d_in[18];
  const float* bhh       = (const float*)d_in[19];
  const float* fc_w      = (const float*)d_in[20];
  const float* fc_b      = (const float*)d_in[21];

  float* preds = (float*)d_out;
  float* probs = preds + (size_t)B_ * TM_ * V_;

  char* w = (char*)d_ws;
  auto alloc = [&](size_t bytes) -> char* {
    char* p = w; w += (bytes + 255) & ~(size_t)255; return p;
  };
  f16* input_h = (f16*)alloc((size_t)6422528 * 2);
  f16* fcw_pad = (f16*)alloc((size_t)512 * VP_ * 2);
  f16* eawT    = (f16*)alloc((size_t)512 * 2048 * 2);   // [n=512][k=2048]
  f16* dawT    = (f16*)alloc((size_t)512 * 512 * 2);    // [512][512]
  f16* avwT    = (f16*)alloc((size_t)2048 * 512 * 2);   // [2048][512]
  f16* whhT    = (f16*)alloc((size_t)2048 * 512 * 2);   // [2048][512]
  f16* wih0T   = (f16*)alloc((size_t)2048 * 512 * 2);   // [2048][512]
  f16* wih2T   = (f16*)alloc((size_t)2048 * 2048 * 2);  // [2048][2048]
  f16* hwT     = (f16*)alloc((size_t)512 * 2048 * 2);   // [512][2048]
  f16* cwT     = (f16*)alloc((size_t)512 * 2048 * 2);   // [512][2048]
  f16* meanh   = (f16*)alloc((size_t)B_ * ENC_ * 2);
  f16* encproj = (f16*)alloc((size_t)3136 * 512 * 2);
  float* hbuf  = (float*)alloc((size_t)B_ * 512 * 4);
  float* cbuf  = (float*)alloc((size_t)B_ * 512 * 4);
  f16*   hh    = (f16*)alloc((size_t)B_ * 512 * 2);
  float* aout  = (float*)alloc((size_t)2 * 64 * 4608 * 4);
  f16*   xg    = (f16*)alloc((size_t)B_ * 2048 * 2);
  float* part  = (float*)alloc((size_t)KS_ * B_ * 2048 * 4);
  f16*   hseq  = (f16*)alloc((size_t)TM_ * B_ * 512 * 2);
  f16*   embal = (f16*)alloc((size_t)TM_ * B_ * 512 * 2);
  float* embpj = (float*)alloc((size_t)TM_ * B_ * 2048 * 4);

  k_castone<<<(6422528 / 4 + 255) / 256, 256, 0, stream>>>(input, input_h, 6422528 / 4);

  TrJobs TJ;
  TJ.s[0] = enc_att_w;           TJ.d[0] = eawT;  TJ.K[0] = 2048; TJ.N[0] = 512;  TJ.tiles[0] = 256;
  TJ.s[1] = dec_att_w;           TJ.d[1] = dawT;  TJ.K[1] = 512;  TJ.N[1] = 512;  TJ.tiles[1] = 64;
  TJ.s[2] = actv_w;              TJ.d[2] = avwT;  TJ.K[2] = 512;  TJ.N[2] = 2048; TJ.tiles[2] = 256;
  TJ.s[3] = whh;                 TJ.d[3] = whhT;  TJ.K[3] = 512;  TJ.N[3] = 2048; TJ.tiles[3] = 256;
  TJ.s[4] = wih;                 TJ.d[4] = wih0T; TJ.K[4] = 512;  TJ.N[4] = 2048; TJ.tiles[4] = 256;
  TJ.s[5] = wih + (size_t)512 * 2048; TJ.d[5] = wih2T; TJ.K[5] = 2048; TJ.N[5] = 2048; TJ.tiles[5] = 1024;
  TJ.s[6] = h_w;                 TJ.d[6] = hwT;   TJ.K[6] = 2048; TJ.N[6] = 512;  TJ.tiles[6] = 256;
  TJ.s[7] = c_w;                 TJ.d[7] = cwT;   TJ.K[7] = 2048; TJ.N[7] = 512;  TJ.tiles[7] = 256;
  k_casttr<<<dim3(1024, 8), 256, 0, stream>>>(TJ);

  k_castpad<<<dim3((VP_ / 4 + 255) / 256, 512), 256, 0, stream>>>(fc_w, fcw_pad);

  k_mean<<<64, 256, 0, stream>>>(input_h, meanh);
  k_embgather<<<TM_ * B_, 128, 0, stream>>>(captions, embw, embal);
  k_h0c0<<<16, 256, 0, stream>>>(meanh, hwT, h_b, cwT, c_b, hbuf, cbuf, hh);
  k_ep<<<dim3(49, 8), 256, 0, stream>>>(input_h, eawT, enc_att_b, encproj);
  k_embproj<<<dim3(TM_, 32), 256, 0, stream>>>(embal, wih0T, bih, bhh, embpj);

  for (int t = 0; t < TM_; t++) {
    kA<<<dim3(72, 2), 256, 0, stream>>>(hh, dawT, avwT, whhT, aout);
    kB<<<64, 512, 0, stream>>>(input_h, encproj, att_w, att_b, aout,
                               dec_att_b, actv_b, lens, xg, probs, t);
    kC<<<dim3(32, KS_), 256, 0, stream>>>(xg, wih2T, part);
    kD<<<dim3(64, 2), 256, 0, stream>>>(part, embpj, aout, lens, hbuf, cbuf,
                                        hh, hseq, t);
  }
  k_fc<<<dim3(59, 157), 256, 0, stream>>>(hseq, fcw_pad, fc_b, lens, preds);
}